// Round 5
// baseline (44.405 us; speedup 1.0000x reference)
//
#include <hip/hip_runtime.h>

#define IN_F 4096
#define OUT_F 11008
#define NCLUST 16
#define TOPK 1024
#define NBLK 256
#define ROWS_PB 43      // 256 * 43 = 11008
#define GRAN_F 1024     // floats per granule (4 KB); 4 granules per row
#define NBUF 6          // LDS buffers per wave -> up to 5 granules (20 KB) in flight

__device__ __forceinline__ float dot4(float4 a, float4 b) {
    return a.x * b.x + a.y * b.y + a.z * b.z + a.w * b.w;
}
__device__ __forceinline__ float wredsum(float v) {
    for (int o = 32; o > 0; o >>= 1) v += __shfl_down(v, o, 64);
    return v;
}
__device__ __forceinline__ float wredmax(float v) {
    for (int o = 32; o > 0; o >>= 1) v = fmaxf(v, __shfl_down(v, o, 64));
    return v;
}
// Raw barrier: does NOT drain vmcnt (keeps W prefetch in flight through the
// select phase). lgkmcnt(0) makes prior LDS writes visible.
__device__ __forceinline__ void barrier_lds() {
    asm volatile("s_waitcnt lgkmcnt(0)" ::: "memory");
    __builtin_amdgcn_s_barrier();
}
// Async DMA of granule g (quarter-row) into LDS buffer lbuf. 4 x 1KB insts.
__device__ __forceinline__ void stage_g(const float* __restrict__ W,
                                        int rbase, int g, float* lbuf, int lane) {
    int row = rbase + 4 * (g >> 2);
    if (row >= OUT_F) row = OUT_F - 1;   // only block 255 / wave 3 / dummy row
    const float* src = W + (size_t)row * IN_F + (g & 3) * GRAN_F + lane * 4;
    #pragma unroll
    for (int j = 0; j < 4; ++j) {
        __builtin_amdgcn_global_load_lds(
            (const __attribute__((address_space(1))) void*)(src + j * 256),
            (__attribute__((address_space(3))) void*)(lbuf + j * 256),
            16, 0, 0);
    }
}

__global__ __launch_bounds__(256, 1) void fused_kernel(
    const float* __restrict__ x,
    const float* __restrict__ W,
    const float* __restrict__ bias,
    const float* __restrict__ centers,
    float* __restrict__ out)
{
    const int tid  = threadIdx.x;
    const int lane = tid & 63;
    const int wid  = tid >> 6;
    const int bid  = blockIdx.x;

    __shared__ __align__(16) float sxm[IN_F];              // e, later masked x (16 KB)
    __shared__ __align__(16) float wstage[4 * NBUF][GRAN_F]; // 96 KB, 6 buffers/wave
    __shared__ unsigned int hist[4][256];                  // wave-private histograms
    __shared__ float sredA[4], sredB[4];
    __shared__ float sdot[NCLUST], scsq[NCLUST];
    __shared__ unsigned int wtot4[4], weq[4];
    __shared__ unsigned int sprefix, sKrem, sG;
    __shared__ int sci;

    const int rbase = bid * ROWS_PB + wid;     // rows rbase + 4*i, i = 0..10
    float* wb = &wstage[wid * NBUF][0];

    // ---- issue x loads first (oldest -> compiler can use counted waits) ----
    float4 x0 = ((const float4*)x)[tid * 4 + 0];
    float4 x1 = ((const float4*)x)[tid * 4 + 1];
    float4 x2 = ((const float4*)x)[tid * 4 + 2];
    float4 x3 = ((const float4*)x)[tid * 4 + 3];

    // ---- bias prefetch (before granule staging: retires first) ----
    float bv[11];
    #pragma unroll
    for (int i = 0; i < 11; ++i) {
        int r = rbase + 4 * i;
        bv[i] = bias[(r < OUT_F) ? r : (OUT_F - 1)];
    }

    // ---- prologue: 6 granules in flight; they LAND during the select phase ----
    #pragma unroll
    for (int g = 0; g < NBUF; ++g) stage_g(W, rbase, g, wb + g * GRAN_F, lane);
    asm volatile("" ::: "memory");

    // ================= SELECT (redundant per block) =================
    // max |x|
    {
        float m = fmaxf(fmaxf(fabsf(x0.x), fabsf(x0.y)), fmaxf(fabsf(x0.z), fabsf(x0.w)));
        m = fmaxf(m, fmaxf(fmaxf(fabsf(x1.x), fabsf(x1.y)), fmaxf(fabsf(x1.z), fabsf(x1.w))));
        m = fmaxf(m, fmaxf(fmaxf(fabsf(x2.x), fabsf(x2.y)), fmaxf(fabsf(x2.z), fabsf(x2.w))));
        m = fmaxf(m, fmaxf(fmaxf(fabsf(x3.x), fabsf(x3.y)), fmaxf(fabsf(x3.z), fabsf(x3.w))));
        m = wredmax(m);
        if (lane == 0) sredA[wid] = m;
    }
    barrier_lds();
    const float mx = fmaxf(fmaxf(sredA[0], sredA[1]), fmaxf(sredA[2], sredA[3]));

    // e = exp(|x| - mx) -> LDS + block sum
    float e[16];
    e[0]=expf(fabsf(x0.x)-mx); e[1]=expf(fabsf(x0.y)-mx); e[2]=expf(fabsf(x0.z)-mx); e[3]=expf(fabsf(x0.w)-mx);
    e[4]=expf(fabsf(x1.x)-mx); e[5]=expf(fabsf(x1.y)-mx); e[6]=expf(fabsf(x1.z)-mx); e[7]=expf(fabsf(x1.w)-mx);
    e[8]=expf(fabsf(x2.x)-mx); e[9]=expf(fabsf(x2.y)-mx); e[10]=expf(fabsf(x2.z)-mx); e[11]=expf(fabsf(x2.w)-mx);
    e[12]=expf(fabsf(x3.x)-mx); e[13]=expf(fabsf(x3.y)-mx); e[14]=expf(fabsf(x3.z)-mx); e[15]=expf(fabsf(x3.w)-mx);
    {
        float4* sxm4 = (float4*)sxm;
        sxm4[tid*4+0] = make_float4(e[0],e[1],e[2],e[3]);
        sxm4[tid*4+1] = make_float4(e[4],e[5],e[6],e[7]);
        sxm4[tid*4+2] = make_float4(e[8],e[9],e[10],e[11]);
        sxm4[tid*4+3] = make_float4(e[12],e[13],e[14],e[15]);
        float s = 0.0f;
        #pragma unroll
        for (int k = 0; k < 16; ++k) s += e[k];
        s = wredsum(s);
        if (lane == 0) sredB[wid] = s;
    }
    barrier_lds();
    const float S = sredB[0] + sredB[1] + sredB[2] + sredB[3];

    // per-cluster dot(c,e), sum(c^2): wave w -> clusters 4w..4w+3
    {
        const float4* e4  = (const float4*)sxm;
        const float*  cb  = centers + (size_t)(4 * wid) * IN_F;
        const float4* c0p = (const float4*)(cb);
        const float4* c1p = (const float4*)(cb + IN_F);
        const float4* c2p = (const float4*)(cb + 2 * IN_F);
        const float4* c3p = (const float4*)(cb + 3 * IN_F);
        float d0=0,d1=0,d2=0,d3=0,q0=0,q1=0,q2=0,q3=0;
        #pragma unroll
        for (int j = 0; j < 16; ++j) {
            int idx = j * 64 + lane;
            float4 ev = e4[idx];
            float4 a = c0p[idx], b = c1p[idx], c = c2p[idx], d = c3p[idx];
            d0 += dot4(a, ev); q0 += dot4(a, a);
            d1 += dot4(b, ev); q1 += dot4(b, b);
            d2 += dot4(c, ev); q2 += dot4(c, c);
            d3 += dot4(d, ev); q3 += dot4(d, d);
        }
        d0 = wredsum(d0); d1 = wredsum(d1); d2 = wredsum(d2); d3 = wredsum(d3);
        q0 = wredsum(q0); q1 = wredsum(q1); q2 = wredsum(q2); q3 = wredsum(q3);
        if (lane == 0) {
            sdot[4*wid+0]=d0; sdot[4*wid+1]=d1; sdot[4*wid+2]=d2; sdot[4*wid+3]=d3;
            scsq[4*wid+0]=q0; scsq[4*wid+1]=q1; scsq[4*wid+2]=q2; scsq[4*wid+3]=q3;
        }
    }
    barrier_lds();

    // argmin_cl [ sum(c^2) - (2/S) dot(c,e) ]  (wave 0; strict < keeps first idx)
    if (wid == 0) {
        float v = (lane < NCLUST) ? (scsq[lane] - (2.0f / S) * sdot[lane]) : 3.0e38f;
        int bi = lane;
        for (int off = 8; off > 0; off >>= 1) {
            float ov = __shfl_down(v, off, 64);
            int   oi = __shfl_down(bi, off, 64);
            if (ov < v) { v = ov; bi = oi; }
        }
        if (lane == 0) sci = bi;
    }
    barrier_lds();
    const int ci = sci;

    // chosen center values (positive floats: uint compare == float compare)
    const float4* cc4 = (const float4*)(centers + (size_t)ci * IN_F);
    float4 c0 = cc4[tid*4+0], c1 = cc4[tid*4+1], c2 = cc4[tid*4+2], c3 = cc4[tid*4+3];
    {
        unsigned int* hflat = &hist[0][0];
        hflat[tid] = 0u; hflat[tid+256] = 0u; hflat[tid+512] = 0u; hflat[tid+768] = 0u;
        if (tid == 0) { sprefix = 0u; sKrem = TOPK; sG = 0u; }
    }
    barrier_lds();

    unsigned int cv[16];
    cv[0]=__float_as_uint(c0.x); cv[1]=__float_as_uint(c0.y); cv[2]=__float_as_uint(c0.z); cv[3]=__float_as_uint(c0.w);
    cv[4]=__float_as_uint(c1.x); cv[5]=__float_as_uint(c1.y); cv[6]=__float_as_uint(c1.z); cv[7]=__float_as_uint(c1.w);
    cv[8]=__float_as_uint(c2.x); cv[9]=__float_as_uint(c2.y); cv[10]=__float_as_uint(c2.z); cv[11]=__float_as_uint(c2.w);
    cv[12]=__float_as_uint(c3.x); cv[13]=__float_as_uint(c3.y); cv[14]=__float_as_uint(c3.z); cv[15]=__float_as_uint(c3.w);

    // ---- 4-pass radix select for the 1024th-largest value ----
    for (int pass = 0; pass < 4; ++pass) {
        const int shift = 24 - 8 * pass;
        const unsigned int pfx  = sprefix;
        const unsigned int krem = sKrem;
        unsigned int* hp = hist[wid];
        #pragma unroll
        for (int k = 0; k < 16; ++k) {
            unsigned int u = cv[k];
            bool cand = (pass == 0) || ((u >> (shift + 8)) == pfx);
            if (cand) atomicAdd(&hp[(u >> shift) & 255u], 1u);
        }
        barrier_lds();
        unsigned int h, s;
        {
            const unsigned int b = tid;
            h = hist[0][b] + hist[1][b] + hist[2][b] + hist[3][b];
            hist[0][b] = 0u; hist[1][b] = 0u; hist[2][b] = 0u; hist[3][b] = 0u;
            s = h;  // suffix-inclusive scan (bins >= b within this wave's 64)
            for (int off = 1; off < 64; off <<= 1) {
                unsigned int v2 = __shfl_down(s, off, 64);
                if (lane + off < 64) s += v2;
            }
            if (lane == 0) wtot4[wid] = s;
        }
        barrier_lds();
        {
            unsigned int add = 0;
            #pragma unroll
            for (int w2 = 0; w2 < 4; ++w2) if (w2 > wid) add += wtot4[w2];
            unsigned int incl = s + add;
            unsigned int excl = incl - h;
            if (excl < krem && krem <= incl) {
                sprefix = (pfx << 8) | (unsigned int)tid;
                sKrem   = krem - excl;
            }
        }
        barrier_lds();
    }
    const unsigned int T = sprefix;

    // ---- tie bookkeeping ----
    unsigned int gt = 0, eq = 0;
    #pragma unroll
    for (int k = 0; k < 16; ++k) {
        gt += (cv[k] > T) ? 1u : 0u;
        eq += (cv[k] == T) ? 1u : 0u;
    }
    {
        unsigned int g = gt;
        for (int o = 32; o > 0; o >>= 1) g += __shfl_down(g, o, 64);
        if (lane == 0) atomicAdd(&sG, g);
    }
    unsigned int p = eq;
    for (int off = 1; off < 64; off <<= 1) {
        unsigned int v2 = __shfl_up(p, off, 64);
        if (lane >= off) p += v2;
    }
    if (lane == 63) weq[wid] = p;
    barrier_lds();
    unsigned int base = p - eq;
    #pragma unroll
    for (int w2 = 0; w2 < 4; ++w2) if (w2 < wid) base += weq[w2];
    const unsigned int needEq = TOPK - sG;

    // ---- emit masked x into LDS, then pull per-lane slice ----
    {
        float xs[16] = {x0.x,x0.y,x0.z,x0.w, x1.x,x1.y,x1.z,x1.w,
                        x2.x,x2.y,x2.z,x2.w, x3.x,x3.y,x3.z,x3.w};
        float os[16];
        unsigned int r = 0;
        #pragma unroll
        for (int k = 0; k < 16; ++k) {
            bool sel = (cv[k] > T) || ((cv[k] == T) && (base + r < needEq));
            os[k] = sel ? xs[k] : 0.0f;
            r += (cv[k] == T) ? 1u : 0u;
        }
        float4* sxm4 = (float4*)sxm;
        sxm4[tid*4+0] = make_float4(os[0],os[1],os[2],os[3]);
        sxm4[tid*4+1] = make_float4(os[4],os[5],os[6],os[7]);
        sxm4[tid*4+2] = make_float4(os[8],os[9],os[10],os[11]);
        sxm4[tid*4+3] = make_float4(os[12],os[13],os[14],os[15]);
    }
    barrier_lds();
    float4 slice[16];
    {
        const float4* sxm4 = (const float4*)sxm;
        #pragma unroll
        for (int k = 0; k < 16; ++k) slice[k] = sxm4[k * 64 + lane];
    }

    // ================= STREAM W: 6-deep static counted-vmcnt pipeline ========
    // Invariant: granule g retired once outstanding <= 4 * (#granules after g).
    // Steady state: wait vmcnt(20) (5 granules in flight), consume g, then
    // re-stage g+6 into the buffer just consumed. 44 granules (11 rows).
#define CONSUME(BUF, Q, ACC) { \
        const float4* bp = (const float4*)(wb + (BUF) * GRAN_F); \
        float4 a0 = bp[0 * 64 + lane]; \
        float4 a1 = bp[1 * 64 + lane]; \
        float4 a2 = bp[2 * 64 + lane]; \
        float4 a3 = bp[3 * 64 + lane]; \
        ACC += dot4(a0, slice[(Q) * 4 + 0]) + dot4(a1, slice[(Q) * 4 + 1]) \
             + dot4(a2, slice[(Q) * 4 + 2]) + dot4(a3, slice[(Q) * 4 + 3]); \
    }
#define STEP(BUF, Q, ACC, GNEXT) { \
        asm volatile("s_waitcnt vmcnt(20)" ::: "memory"); \
        CONSUME(BUF, Q, ACC); \
        asm volatile("s_waitcnt lgkmcnt(0)" ::: "memory"); \
        stage_g(W, rbase, (GNEXT), wb + (BUF) * GRAN_F, lane); \
    }

    // rows 0..8: 3 super-iterations of 3 rows (12 granules, buffers 0..5,0..5)
    for (int ii = 0; ii < 3; ++ii) {
        const int g0 = ii * 12;
        {   // row i = 3*ii
            float acc = 0.0f;
            STEP(0, 0, acc, g0 + 6);  STEP(1, 1, acc, g0 + 7);
            STEP(2, 2, acc, g0 + 8);  STEP(3, 3, acc, g0 + 9);
            acc = wredsum(acc);
            const int row = rbase + 4 * (3 * ii);
            if (lane == 0) out[row] = acc + bv[3 * ii];
        }
        {   // row i = 3*ii + 1
            float acc = 0.0f;
            STEP(4, 0, acc, g0 + 10); STEP(5, 1, acc, g0 + 11);
            STEP(0, 2, acc, g0 + 12); STEP(1, 3, acc, g0 + 13);
            acc = wredsum(acc);
            const int row = rbase + 4 * (3 * ii + 1);
            if (lane == 0) out[row] = acc + bv[3 * ii + 1];
        }
        {   // row i = 3*ii + 2
            float acc = 0.0f;
            STEP(2, 0, acc, g0 + 14); STEP(3, 1, acc, g0 + 15);
            STEP(4, 2, acc, g0 + 16); STEP(5, 3, acc, g0 + 17);
            acc = wredsum(acc);
            const int row = rbase + 4 * (3 * ii + 2);
            if (lane == 0) out[row] = acc + bv[3 * ii + 2];
        }
    }
    // row 9: granules 36..39 (buffers 0..3); stage 42,43 (buffers 0,1)
    {
        float acc = 0.0f;
        STEP(0, 0, acc, 42);
        STEP(1, 1, acc, 43);
        asm volatile("s_waitcnt vmcnt(20)" ::: "memory"); CONSUME(2, 2, acc);
        asm volatile("s_waitcnt vmcnt(16)" ::: "memory"); CONSUME(3, 3, acc);
        acc = wredsum(acc);
        const int row = rbase + 36;
        if (lane == 0) out[row] = acc + bv[9];
    }
    // row 10: granules 40..43 (buffers 4,5,0,1); may be dummy for last block
    {
        float acc = 0.0f;
        asm volatile("s_waitcnt vmcnt(12)" ::: "memory"); CONSUME(4, 0, acc);
        asm volatile("s_waitcnt vmcnt(8)"  ::: "memory"); CONSUME(5, 1, acc);
        asm volatile("s_waitcnt vmcnt(4)"  ::: "memory"); CONSUME(0, 2, acc);
        asm volatile("s_waitcnt vmcnt(0)"  ::: "memory"); CONSUME(1, 3, acc);
        acc = wredsum(acc);
        const int row = rbase + 40;
        if (lane == 0 && row < OUT_F) out[row] = acc + bv[10];
    }
#undef STEP
#undef CONSUME
}

extern "C" void kernel_launch(void* const* d_in, const int* in_sizes, int n_in,
                              void* d_out, int out_size, void* d_ws, size_t ws_size,
                              hipStream_t stream) {
    const float* x       = (const float*)d_in[0];  // [1,1,4096]
    const float* weight  = (const float*)d_in[1];  // [11008,4096]
    const float* bias    = (const float*)d_in[2];  // [11008]
    const float* centers = (const float*)d_in[3];  // [16,4096]
    float* out = (float*)d_out;                    // [11008]

    fused_kernel<<<NBLK, 256, 0, stream>>>(x, weight, bias, centers, out);
}